// Round 11
// baseline (145.123 us; speedup 1.0000x reference)
//
#include <hip/hip_runtime.h>
#include <hip/hip_bf16.h>
#include <stdint.h>
#include <stddef.h>

typedef unsigned short u16;
typedef unsigned int   u32;
typedef __attribute__((ext_vector_type(8))) short bf16x8;  // 8 bf16 = 4 VGPRs
typedef __attribute__((ext_vector_type(4))) float f32x4;   // MFMA C/D

#define LOG2E   1.44269504f
#define EXP_OFF 23.0831206f   // 16 * log2(e)

static __device__ __forceinline__ float bf2f(u16 v) {
    u32 u = ((u32)v) << 16; float f; __builtin_memcpy(&f, &u, 4); return f;
}
static __device__ __forceinline__ u16 f2bf(float f) {
    u32 u; __builtin_memcpy(&u, &f, 4);
    u32 r = (u + 0x7fffu + ((u >> 16) & 1u)) >> 16; return (u16)r;
}
static __device__ __forceinline__ float as_f(u32 u) { float f; __builtin_memcpy(&f, &u, 4); return f; }
static __device__ __forceinline__ u32   as_u(float f) { u32 u; __builtin_memcpy(&u, &f, 4); return u; }

// fp32-vs-bf16 input detection (wave 0)
static __device__ __forceinline__ int detect_f32_wave0(const void* x, int t) {
    const u32* xw = (const u32*)x;
    int bad = 0;
    #pragma unroll
    for (int k = 0; k < 4; ++k) {
        u32 wv = xw[(t << 2) + k];
        int e = (wv >> 7) & 0xff;
        bad += (e >= 160);
    }
    unsigned long long m = __ballot(bad > 0);
    return (__popcll(m) >= 8) ? 1 : 0;
}

// V workspace layout (pre-fragmented for MFMA B-operand, per batch):
//   elem_addr = cblk*65536 + jblk*512 + (quad4*16 + clo)*8 + jlo
//   where c = cblk*16 + clo, j = jblk*32 + quad4*8 + jlo.
// A wave B-frag load (lane = quad*16+n16 reads 16B) is 1KB fully contiguous.

// ---------------------------------------------------------------------------
// Kernel 1 (MFMA proj, unchanged — verified at R1):
// ---------------------------------------------------------------------------
__global__ __launch_bounds__(256) void qkv_proj_mfma(
    const void* __restrict__ x,
    const void* __restrict__ Wq, const void* __restrict__ bq,
    const void* __restrict__ Wk, const void* __restrict__ bk,
    const void* __restrict__ Wv, const void* __restrict__ bv,
    u16* __restrict__ qws, u16* __restrict__ kws, u16* __restrict__ vws,
    int n_off, int nshiftp)
{
    __shared__ u16 Wl[64 * 256];   // 32 KB, swizzled bf16 W-slice
    __shared__ int dtf;

    const int t    = threadIdx.x;
    const int bid  = blockIdx.x;
    const int n_w  = bid & ((1 << nshiftp) - 1);
    const int rest = bid >> nshiftp;
    const int g    = rest % 5;        // 0 = q+k, 1..4 = v quarters
    const int it   = rest / 5;        // i-tile (64 i)
    const int n_g  = n_off + n_w;
    const int i0   = it << 6;

    if (t < 64) { int f = detect_f32_wave0(x, t); if (t == 0) dtf = f; }
    __syncthreads();
    const bool isf32 = (dtf != 0);

    // ---- stage W slice (64 rows x 256 cols) into LDS, swizzled bf16 ----
    #pragma unroll
    for (int k = 0; k < 16; ++k) {
        int idx  = t + (k << 8);
        int row  = idx >> 6;            // 0..63 (wave-uniform per k)
        int col4 = (idx & 63) << 2;     // 0..252 step 4
        const void* src; int srow;
        if (g == 0) {
            if (row < 32) { src = Wq; srow = row; }
            else          { src = Wk; srow = row - 32; }
        } else { src = Wv; srow = ((g - 1) << 6) + row; }
        ushort4 h;
        if (isf32) {
            float4 wv = *((const float4*)((const float*)src + srow * 256 + col4));
            h.x = f2bf(wv.x); h.y = f2bf(wv.y); h.z = f2bf(wv.z); h.w = f2bf(wv.w);
        } else {
            h = *((const ushort4*)((const u16*)src + srow * 256 + col4));
        }
        *(ushort4*)&Wl[(row << 8) + (col4 ^ ((row & 7) << 3))] = h;
    }
    __syncthreads();

    const int lane = t & 63;
    const int w    = t >> 6;          // wave -> i-frag
    const int n16  = lane & 15;
    const int quad = lane >> 4;
    const int i_b  = i0 + (w << 4);
    const int i    = i_b + n16;
    const int swz  = (n16 & 7) << 3;

    f32x4 acc[4];
    #pragma unroll
    for (int f = 0; f < 4; ++f) acc[f] = (f32x4){0.f, 0.f, 0.f, 0.f};

    // ---- k-loop: 8 chunks of 32 c; A direct-global, B from LDS ----
    if (isf32) {
        const float* xp = (const float*)x
            + (((size_t)(n_g * 256 + (quad << 3))) << 12) + i;
        float af[8];
        #pragma unroll
        for (int e = 0; e < 8; ++e) af[e] = xp[(size_t)e << 12];
        #pragma unroll
        for (int c8 = 0; c8 < 8; ++c8) {
            bf16x8 a;
            #pragma unroll
            for (int e = 0; e < 8; ++e) a[e] = (short)f2bf(af[e]);
            if (c8 < 7) {
                const float* xn = xp + (((size_t)(c8 + 1) << 5) << 12);
                #pragma unroll
                for (int e = 0; e < 8; ++e) af[e] = xn[(size_t)e << 12];
            }
            const int c0 = c8 << 5;
            #pragma unroll
            for (int f = 0; f < 4; ++f) {
                const int brow = (f << 4) + n16;
                bf16x8 b = *(const bf16x8*)
                    &Wl[(brow << 8) + ((c0 + (quad << 3)) ^ swz)];
                acc[f] = __builtin_amdgcn_mfma_f32_16x16x32_bf16(a, b, acc[f], 0, 0, 0);
            }
        }
    } else {
        const u16* xp = (const u16*)x
            + (((size_t)(n_g * 256 + (quad << 3))) << 12) + i;
        u16 af[8];
        #pragma unroll
        for (int e = 0; e < 8; ++e) af[e] = xp[(size_t)e << 12];
        #pragma unroll
        for (int c8 = 0; c8 < 8; ++c8) {
            bf16x8 a;
            #pragma unroll
            for (int e = 0; e < 8; ++e) a[e] = (short)af[e];
            if (c8 < 7) {
                const u16* xn = xp + (((size_t)(c8 + 1) << 5) << 12);
                #pragma unroll
                for (int e = 0; e < 8; ++e) af[e] = xn[(size_t)e << 12];
            }
            const int c0 = c8 << 5;
            #pragma unroll
            for (int f = 0; f < 4; ++f) {
                const int brow = (f << 4) + n16;
                bf16x8 b = *(const bf16x8*)
                    &Wl[(brow << 8) + ((c0 + (quad << 3)) ^ swz)];
                acc[f] = __builtin_amdgcn_mfma_f32_16x16x32_bf16(a, b, acc[f], 0, 0, 0);
            }
        }
    }

    // ---- epilogue: D frag is (col = n16 = och-local, row = quad*4+r = i) ----
    if (g == 0) {
        #pragma unroll
        for (int f = 0; f < 4; ++f) {
            const int ol   = (f << 4) + n16;     // 0..63
            const bool isq = (ol < 32);
            const int och  = isq ? ol : (ol - 32);
            float bias;
            if (isf32) bias = ((const float*)(isq ? bq : bk))[och];
            else       bias = bf2f(((const u16*)(isq ? bq : bk))[och]);
            u16* dst = (isq ? qws : kws) + (((size_t)n_w) << 17) + och;
            const float scale = isq ? LOG2E : 1.0f;
            #pragma unroll
            for (int r = 0; r < 4; ++r) {
                const int ii = i_b + (quad << 2) + r;
                dst[(size_t)ii << 5] = f2bf((acc[f][r] + bias) * scale);
            }
        }
    } else {
        #pragma unroll
        for (int f = 0; f < 4; ++f) {
            const int c = ((g - 1) << 6) + (f << 4) + n16;   // c&15 == n16
            float bias = isf32 ? ((const float*)bv)[c]
                               : bf2f(((const u16*)bv)[c]);
            const int i4 = i_b + (quad << 2);
            ushort4 h;
            h.x = f2bf(acc[f][0] + bias);
            h.y = f2bf(acc[f][1] + bias);
            h.z = f2bf(acc[f][2] + bias);
            h.w = f2bf(acc[f][3] + bias);
            const size_t addr = ((size_t)n_w << 20)
                + ((size_t)(c >> 4) << 16)          // cblk*65536
                + ((size_t)(i4 >> 5) << 9)          // jblk*512
                + (size_t)((((((i4 & 31) >> 3) << 4) + (c & 15)) << 3) + (i4 & 7));
            *(ushort4*)(vws + addr) = h;
        }
    }
}

// --- flash helpers: plain __forceinline__ (R5-proven style) ---
static __device__ __forceinline__ void s_tile16(
    const bf16x8 qfrag, const bf16x8 kc, char* __restrict__ PsW,
    float* __restrict__ lp, const int* __restrict__ pwoff)
{
    const f32x4 zoff = {-EXP_OFF, -EXP_OFF, -EXP_OFF, -EXP_OFF};
    f32x4 s = __builtin_amdgcn_mfma_f32_16x16x32_bf16(qfrag, kc, zoff, 0, 0, 0);
    #pragma unroll
    for (int r = 0; r < 4; ++r) {
        float p = exp2f(s[r]);
        u32 u = as_u(p) & 0xffff0000u;
        lp[r] += as_f(u);
        *(u16*)(PsW + pwoff[r]) = (u16)(u >> 16);
    }
}

static __device__ __forceinline__ void pa_load(
    const char* __restrict__ PsR, const int* __restrict__ paoff, bf16x8* pa)
{
    #pragma unroll
    for (int qs = 0; qs < 4; ++qs)
        pa[qs] = *(const bf16x8*)(PsR + paoff[qs]);
}

static __device__ __forceinline__ void pv_tile16(
    const bf16x8* pa, const bf16x8 v0, const bf16x8 v1, f32x4 acc[4][2])
{
    #pragma unroll
    for (int qs = 0; qs < 4; ++qs) {
        acc[qs][0] = __builtin_amdgcn_mfma_f32_16x16x32_bf16(pa[qs], v0, acc[qs][0], 0, 0, 0);
        acc[qs][1] = __builtin_amdgcn_mfma_f32_16x16x32_bf16(pa[qs], v1, acc[qs][1], 0, 0, 0);
    }
}

// ---------------------------------------------------------------------------
// Kernel 2 (v16): v11b's 2-tile phase structure with the V-cover bug FIXED.
//   - 2 tiles/phase, 4 P buffers (32 KB), 32 barriers (v12 had 64)
//   - V for PV(2p,2p+1) issued at END of phase p, consumed END of phase p+1
//     (cover ~3100cy; v11b's fatal flaw was same-phase issue+consume)
//   - K double-buffered, issued at phase start (R6-validated, cover ~1 phase)
//   - pa ds_reads hoisted to phase start (lgkm cover under S)
//   - hoisted LDS offsets, -EXP_OFF fold, static parity bases (R10-proven)
// ---------------------------------------------------------------------------
__global__ __launch_bounds__(1024) void flash_mfma13(
    const u16* __restrict__ qws, const u16* __restrict__ kws,
    const u16* __restrict__ vws, void* __restrict__ out,
    const void* __restrict__ x, int n_off, int nshift)
{
    __shared__ __align__(16) char arena[32768];   // 4 P buffers of 8 KB
    __shared__ __align__(16) float lS[64];
    __shared__ int dtf;
    char* buf0 = arena;              // tiles even-pair slot 0
    char* buf1 = arena + 8192;
    char* buf2 = arena + 16384;
    char* buf3 = arena + 24576;
    float* Dbuf = (float*)arena;     // epilogue alias

    const int t    = threadIdx.x;
    const int lane = t & 63;
    const int w    = t >> 6;          // 0..15
    const int n16  = lane & 15;
    const int quad = lane >> 4;
    const int bid  = blockIdx.x;
    const int n_w  = bid & ((1 << nshift) - 1);
    const int qt   = bid >> nshift;
    const int n_g  = n_off + n_w;
    const int i0   = qt << 6;

    if (t < 64) {
        int f = detect_f32_wave0(x, t);
        if (t == 0) dtf = f;
        lS[t] = 0.f;
    }

    const u16* qb = qws + (((size_t)n_w) << 17);
    const u16* kb = kws + (((size_t)n_w) << 17);
    const u16* vb = vws + (((size_t)n_w) << 20);

    // S decomposition
    const int qsub_s = w & 3;
    const int jsub   = w >> 2;
    // PV decomposition: 32 c x 32 j per wave
    const int cq = w & 7;
    const int jq = w >> 3;

    const bf16x8 qfrag =
        *(const bf16x8*)(qb + ((size_t)(i0 + (qsub_s << 4) + n16) << 5) + (quad << 3));

    f32x4 acc[4][2];
    #pragma unroll
    for (int a = 0; a < 4; ++a)
        #pragma unroll
        for (int b = 0; b < 2; ++b) acc[a][b] = (f32x4){0.f, 0.f, 0.f, 0.f};
    float lp[4] = {0.f, 0.f, 0.f, 0.f};

    const int jcol = (jsub << 4) + n16;
    const int j8   = jcol >> 3;
    const int jlo  = jcol & 7;
    const int ksw  = (jq << 2) + quad;

    // hoisted LDS byte offsets (tile-invariant)
    int pwoff[4];
    #pragma unroll
    for (int r = 0; r < 4; ++r) {
        const int qrow = (qsub_s << 4) + (quad << 2) + r;
        pwoff[r] = (qrow * 64 + ((j8 ^ (qrow & 7)) << 3) + jlo) << 1;
    }
    int paoff[4];
    #pragma unroll
    for (int qs = 0; qs < 4; ++qs) {
        const int qrow = (qs << 4) + n16;
        paoff[qs] = (qrow * 64 + ((ksw ^ (qrow & 7)) << 3)) << 1;
    }

    // K frag pointer: K(T) at kp + T*2048 elems
    const u16* kp = kb + ((size_t)((jsub << 4) + n16) << 5) + (quad << 3);
    // Pre-fragmented V: frag(T, cs) at vfp{0,1} + T*1024 elems
    const u16* vfp0 = vb + ((size_t)(cq << 1) << 16) + ((size_t)jq << 9)
                         + ((size_t)((quad << 4) + n16) << 3);
    const u16* vfp1 = vfp0 + 65536;

    bf16x8 kc0, kc1, kn0, kn1;
    bf16x8 vA0, vA1, vA2, vA3;   // V set A
    bf16x8 vB0, vB1, vB2, vB3;   // V set B
    bf16x8 pa[4];

    // ---- prologue (phase 0): S(0)->buf0, S(1)->buf1; K(2),K(3); V(0),V(1) (set A) ----
    kc0 = *(const bf16x8*)(kp);
    kc1 = *(const bf16x8*)(kp + 2048);
    s_tile16(qfrag, kc0, buf0, lp, pwoff);
    s_tile16(qfrag, kc1, buf1, lp, pwoff);
    kn0 = *(const bf16x8*)(kp + 2 * 2048);
    kn1 = *(const bf16x8*)(kp + 3 * 2048);
    vA0 = *(const bf16x8*)(vfp0);          // V(0)
    vA1 = *(const bf16x8*)(vfp1);
    vA2 = *(const bf16x8*)(vfp0 + 1024);   // V(1)
    vA3 = *(const bf16x8*)(vfp1 + 1024);
    __syncthreads();

    // ---- pair loop: phases {1,2},{3,4},...,{29,30} ----
    const u16* kpp  = kp + 4 * 2048;     // phase 1 loads K(4),K(5)
    const u16* vpp0 = vfp0 + 2 * 1024;   // phase 1 loads V(2),V(3)
    const u16* vpp1 = vfp1 + 2 * 1024;

    for (int pr = 0; pr < 15; ++pr) {
        // ===== odd phase p = 2*pr+1: W={buf2,buf3}, R={buf0,buf1},
        //       consume V set A, load V set B =====
        kc0 = kn0; kc1 = kn1;
        kn0 = *(const bf16x8*)(kpp);
        kn1 = *(const bf16x8*)(kpp + 2048);
        kpp += 4096;
        pa_load(buf0, paoff, pa);                     // tile 2p-2
        s_tile16(qfrag, kc0, buf2, lp, pwoff);        // S(2p)
        pv_tile16(pa, vA0, vA1, acc);                 // PV(2p-2)
        pa_load(buf1, paoff, pa);                     // tile 2p-1
        s_tile16(qfrag, kc1, buf3, lp, pwoff);        // S(2p+1)
        pv_tile16(pa, vA2, vA3, acc);                 // PV(2p-1)
        vB0 = *(const bf16x8*)(vpp0);                 // V(2p)
        vB1 = *(const bf16x8*)(vpp1);
        vB2 = *(const bf16x8*)(vpp0 + 1024);          // V(2p+1)
        vB3 = *(const bf16x8*)(vpp1 + 1024);
        vpp0 += 2048; vpp1 += 2048;
        __syncthreads();

        // ===== even phase p+1: W={buf0,buf1}, R={buf2,buf3},
        //       consume V set B, load V set A =====
        kc0 = kn0; kc1 = kn1;
        kn0 = *(const bf16x8*)(kpp);
        kn1 = *(const bf16x8*)(kpp + 2048);
        kpp += 4096;
        pa_load(buf2, paoff, pa);                     // tile 2p
        s_tile16(qfrag, kc0, buf0, lp, pwoff);        // S(2p+2)
        pv_tile16(pa, vB0, vB1, acc);                 // PV(2p)
        pa_load(buf3, paoff, pa);                     // tile 2p+1
        s_tile16(qfrag, kc1, buf1, lp, pwoff);        // S(2p+3)
        pv_tile16(pa, vB2, vB3, acc);                 // PV(2p+1)
        vA0 = *(const bf16x8*)(vpp0);                 // V(2p+2)
        vA1 = *(const bf16x8*)(vpp1);
        vA2 = *(const bf16x8*)(vpp0 + 1024);          // V(2p+3)
        vA3 = *(const bf16x8*)(vpp1 + 1024);
        vpp0 += 2048; vpp1 += 2048;
        __syncthreads();
    }

    // ===== peeled phase 31 (odd): W={buf2,buf3}, R={buf0,buf1},
    //       consume set A (V(60),V(61)), load set B (V(62),V(63)) =====
    {
        kc0 = kn0; kc1 = kn1;                         // K(62), K(63)
        pa_load(buf0, paoff, pa);                     // tile 60
        s_tile16(qfrag, kc0, buf2, lp, pwoff);        // S(62)
        pv_tile16(pa, vA0, vA1, acc);                 // PV(60)
        pa_load(buf1, paoff, pa);                     // tile 61
        s_tile16(qfrag, kc1, buf3, lp, pwoff);        // S(63)
        pv_tile16(pa, vA2, vA3, acc);                 // PV(61)
        vB0 = *(const bf16x8*)(vpp0);                 // V(62)
        vB1 = *(const bf16x8*)(vpp1);
        vB2 = *(const bf16x8*)(vpp0 + 1024);          // V(63)
        vB3 = *(const bf16x8*)(vpp1 + 1024);
        __syncthreads();
    }

    // ---- final: PV(62), PV(63) from {buf2,buf3} with set B ----
    {
        pa_load(buf2, paoff, pa);
        pv_tile16(pa, vB0, vB1, acc);
        pa_load(buf3, paoff, pa);
        pv_tile16(pa, vB2, vB3, acc);
    }

    // ---- l reduction ----
    #pragma unroll
    for (int r = 0; r < 4; ++r) {
        lp[r] += __shfl_xor(lp[r], 1);
        lp[r] += __shfl_xor(lp[r], 2);
        lp[r] += __shfl_xor(lp[r], 4);
        lp[r] += __shfl_xor(lp[r], 8);
    }
    if (n16 == 0) {
        #pragma unroll
        for (int r = 0; r < 4; ++r)
            atomicAdd(&lS[(qsub_s << 4) + (quad << 2) + r], lp[r]);
    }
    __syncthreads();
    if (t < 64) lS[t] = 1.0f / lS[t];
    const bool isf32 = (dtf != 0);

    // ---- epilogue: 4 chunks of 64 c; combine jq-partials in Dbuf, store ----
    for (int chunk = 0; chunk < 4; ++chunk) {
        __syncthreads();   // Dbuf free; rl ready; Ps reads complete (chunk 0)
        if (jq == 1 && (cq >> 1) == chunk) {
            #pragma unroll
            for (int qs = 0; qs < 4; ++qs)
                #pragma unroll
                for (int cs = 0; cs < 2; ++cs)
                    *(f32x4*)&Dbuf[(((cq & 1) << 5) + (cs << 4) + n16) * 68 +
                                   (qs << 4) + (quad << 2)] = acc[qs][cs];
        }
        __syncthreads();
        if (jq == 0 && (cq >> 1) == chunk) {
            #pragma unroll
            for (int qs = 0; qs < 4; ++qs)
                #pragma unroll
                for (int cs = 0; cs < 2; ++cs) {
                    float* p = &Dbuf[(((cq & 1) << 5) + (cs << 4) + n16) * 68 +
                                     (qs << 4) + (quad << 2)];
                    f32x4 d = *(f32x4*)p;
                    d += acc[qs][cs];
                    *(f32x4*)p = d;
                }
        }
        __syncthreads();
        // store: 1024 threads x 4 q
        const int c_l = t >> 4;
        const int qg  = (t & 15) << 2;
        float4 d  = *(float4*)&Dbuf[c_l * 68 + qg];
        float4 rl = *(float4*)&lS[qg];
        const int c_glob = (chunk << 6) + c_l;
        const size_t ob = (((size_t)(n_g * 256 + c_glob)) << 12) + i0 + qg;
        if (isf32) {
            float4 o = make_float4(d.x * rl.x, d.y * rl.y, d.z * rl.z, d.w * rl.w);
            *(float4*)((float*)out + ob) = o;
        } else {
            union { uint2 v; u16 h[4]; } o;
            o.h[0] = f2bf(d.x * rl.x);
            o.h[1] = f2bf(d.y * rl.y);
            o.h[2] = f2bf(d.z * rl.z);
            o.h[3] = f2bf(d.w * rl.w);
            *(uint2*)((u16*)out + ob) = o.v;
        }
    }
}

extern "C" void kernel_launch(void* const* d_in, const int* in_sizes, int n_in,
                              void* d_out, int out_size, void* d_ws, size_t ws_size,
                              hipStream_t stream)
{
    const void* x  = d_in[0];
    const void* Wq = d_in[1];
    const void* bq = d_in[2];
    const void* Wk = d_in[3];
    const void* bk = d_in[4];
    const void* Wv = d_in[5];
    const void* bv = d_in[6];

    const size_t full_need = (size_t)(4u * 4096u) * (32 + 32 + 256) * 2; // 10 MB
    if (ws_size >= full_need) {
        u16* qws = (u16*)d_ws;
        u16* kws = qws + (size_t)4 * 4096 * 32;
        u16* vws = kws + (size_t)4 * 4096 * 32;
        qkv_proj_mfma<<<dim3(1280), dim3(256), 0, stream>>>(
            x, Wq, bq, Wk, bk, Wv, bv, qws, kws, vws, 0, 2);
        flash_mfma13<<<dim3(256), dim3(1024), 0, stream>>>(
            qws, kws, vws, d_out, x, 0, 2);
    } else {
        u16* qws = (u16*)d_ws;
        u16* kws = qws + (size_t)4096 * 32;
        u16* vws = kws + (size_t)4096 * 32;
        for (int n = 0; n < 4; ++n) {
            qkv_proj_mfma<<<dim3(320), dim3(256), 0, stream>>>(
                x, Wq, bq, Wk, bk, Wv, bv, qws, kws, vws, n, 0);
            flash_mfma13<<<dim3(64), dim3(1024), 0, stream>>>(
                qws, kws, vws, d_out, x, n, 0);
        }
    }
}